// Round 16
// baseline (777.459 us; speedup 1.0000x reference)
//
#include <hip/hip_runtime.h>
#include <math.h>

#define HW 65536
#define DD 160
#define NB 2
#define DCH 40
#define NSL (DCH + 6)   // 46 marched slices per chunk incl. halo
#define NCH 4
#define TW 32
#define TH 8
#define PH 15           // h-pitch (14 rows + 1 pad, odd)

#define SSIM_C1 1e-4f
#define SSIM_C2 9e-4f

typedef float f32x2 __attribute__((ext_vector_type(2)));

struct Gw { float g[7]; };

static __device__ __forceinline__ f32x2 s2(float v) { f32x2 r; r.x = v; r.y = v; return r; }

// Fused SSIM3D v16: paired slices — TWO slices per barrier (24 barriers vs 47).
// TH=8 tiles, 2048 blocks. Pair-phase m: waves 0-1 W-conv slice 2m, waves 2-3
// W-conv slice 2m+1 (parallel) into plane slots (m&1)*2+{0,1}; each W-thread
// then issues 20 raw loads for its slice of pair m+1 (depth-2 in slices);
// H+D for slices 2m-2, 2m-1 from the opposite slot pair; one __syncthreads.
// u/v algebra (4 fields, 2 packed planes) and multiplier masking from v15.
// 14-pair unroll keeps slot parity and ring indices compile-time.
__global__ __launch_bounds__(256, 2) void k_fused(
    const float* __restrict__ img1, const float* __restrict__ img2,
    Gw gw, float* __restrict__ partials)
{
    __shared__ f32x2 pUV[4][TW][PH];   // slot: (pair&1)*2 + slice-parity
    __shared__ f32x2 pSQ[4][TW][PH];
    __shared__ float red[256];

    const int tid = threadIdx.x;
    const int nb = blockIdx.z >> 2;
    const int o0 = (blockIdx.z & 3) * DCH;
    const int h0 = blockIdx.y * TH;
    const int w0 = blockIdx.x * TW;
    const float* i1 = img1 + (size_t)nb * DD * HW;
    const float* i2 = img2 + (size_t)nb * DD * HW;

    // ---- W geometry: group 0 = waves 0-1 (even slice), group 1 = waves 2-3 ----
    const int wgrp = tid >> 7;         // 0 or 1
    const int wt = tid & 127;          // task within group
    const bool wth = (wt < 112);       // 14 rows x 8 quads
    const int hh = wt >> 3;            // 0..13
    const int wb = (wt & 7) * 4;
    const int gh = h0 - 3 + hh;
    const int gwb = w0 - 3 + wb;
    const bool ghv = wth && ((unsigned)gh < 256u);
    const int ghc = gh < 0 ? 0 : (gh > 255 ? 255 : gh);
    int coff[10];
    float mx[10];
#pragma unroll
    for (int i = 0; i < 10; ++i) {
        int gwi = gwb + i;
        int gc = gwi < 0 ? 0 : (gwi > 255 ? 255 : gwi);
        coff[i] = ghc * 256 + gc;                      // always-in-bounds address
        mx[i] = (ghv && gwi == gc) ? 1.f : 0.f;        // zero-pad multiplier
    }

    // ---- H/D geometry: 1 output column per thread ----
    const int wcol = tid & 31;
    const int hrow = tid >> 5;         // 0..7

    f32x2 ringUV[7] = {};
    f32x2 ringSQ[7] = {};
    float lsum = 0.f;
    f32x2 cxy[10];   // this thread's slice window (raw x,y), depth-2 pipeline

    // raw slice loader: 20 independent loads, NO dependent VALU at issue site
    auto LOADTO = [&](int s) {
        const float* p1 = i1 + (size_t)s * HW;
        const float* p2 = i2 + (size_t)s * HW;
#pragma unroll
        for (int i = 0; i < 10; ++i) cxy[i].x = p1[coff[i]];
#pragma unroll
        for (int i = 0; i < 10; ++i) cxy[i].y = p2[coff[i]];
    };

    // prologue: pair 0's W slices are r = 0 (grp0) / 1 (grp1)
    {
        const int s0 = o0 - 3 + wgrp;
        if (s0 >= 0 && wth) LOADTO(s0);
    }

#define PAIR(J)                                                               \
    {                                                                         \
        const int m = 14 * t2 + (J);                                          \
        if (m <= 23) {                                                        \
            const int rW = 2 * m + wgrp;                                      \
            const int sW = o0 - 3 + rW;                                       \
            /* 1) W-pass consumes cxy (loaded at pair m-1) */                 \
            if (wth && rW < NSL && sW >= 0 && sW < DD) {                      \
                f32x2 aUV[4] = {};                                            \
                f32x2 aSQ[4] = {};                                            \
                _Pragma("unroll")                                             \
                for (int i = 0; i < 10; ++i) {                                \
                    f32x2 uv;                                                 \
                    uv.x = cxy[i].x + cxy[i].y;                               \
                    uv.y = cxy[i].x - cxy[i].y;                               \
                    uv = uv * s2(mx[i]);                                      \
                    const f32x2 sq = uv * uv;                                 \
                    _Pragma("unroll")                                         \
                    for (int o = 0; o < 4; ++o) {                             \
                        const int k = i - o;                                  \
                        if (k >= 0 && k < 7) {                                \
                            const float gk = gw.g[k];                         \
                            aUV[o] += s2(gk) * uv;                            \
                            aSQ[o] += s2(gk) * sq;                            \
                        }                                                     \
                    }                                                         \
                }                                                             \
                const int slot = ((J) & 1) * 2 + wgrp;                        \
                _Pragma("unroll")                                             \
                for (int o = 0; o < 4; ++o) {                                 \
                    pUV[slot][wb + o][hh] = aUV[o];                           \
                    pSQ[slot][wb + o][hh] = aSQ[o];                           \
                }                                                             \
            }                                                                 \
            /* 2) depth-2 prefetch: this thread's slice of pair m+1 */        \
            {                                                                 \
                const int sn = sW + 2;                                        \
                if (wth && (rW + 2 < NSL) && sn >= 0 && sn < DD)              \
                    LOADTO(sn);                                               \
            }                                                                 \
            /* 3) H-pass + D-ring + SSIM for slices 2m-2, 2m-1 */             \
            _Pragma("unroll")                                                 \
            for (int q = 0; q < 2; ++q) {                                     \
                const int rh = 2 * m - 2 + q;                                 \
                const int ri = (2 * (J) + 5 + q) % 7;   /* rh mod 7 */        \
                if (rh >= 0 && rh < NSL) {                                    \
                    const int sh = o0 - 3 + rh;                               \
                    if (sh >= 0 && sh < DD) {                                 \
                        const int slot = (((J) + 1) & 1) * 2 + q;             \
                        f32x2 vU[7], vS[7];                                   \
                        _Pragma("unroll")                                     \
                        for (int i = 0; i < 7; ++i) {                         \
                            vU[i] = pUV[slot][wcol][hrow + i];                \
                            vS[i] = pSQ[slot][wcol][hrow + i];                \
                        }                                                     \
                        f32x2 aU = s2(0.f), aS = s2(0.f);                     \
                        _Pragma("unroll")                                     \
                        for (int k = 0; k < 7; ++k) {                         \
                            const float gk = gw.g[k];                         \
                            aU += s2(gk) * vU[k];                             \
                            aS += s2(gk) * vS[k];                             \
                        }                                                     \
                        ringUV[ri] = aU;                                      \
                        ringSQ[ri] = aS;                                      \
                    } else {                                                  \
                        ringUV[ri] = s2(0.f);                                 \
                        ringSQ[ri] = s2(0.f);                                 \
                    }                                                         \
                    if (rh >= 6) {                                            \
                        f32x2 cU = s2(0.f), cS = s2(0.f);                     \
                        _Pragma("unroll")                                     \
                        for (int k = 0; k < 7; ++k) {                         \
                            const float gk = gw.g[k];                         \
                            const int pp = (ri + 1 + k) % 7;                  \
                            cU += s2(gk) * ringUV[pp];                        \
                            cS += s2(gk) * ringSQ[pp];                        \
                        }                                                     \
                        /* A=conv(u), B=conv(v), P=conv(u^2), Q=conv(v^2) */  \
                        const f32x2 ab2 = cU * cU;                            \
                        const float sAB = ab2.x + ab2.y;                      \
                        const float dAB = ab2.x - ab2.y;                      \
                        const float sPQ = cS.x + cS.y;                        \
                        const float dPQ = cS.x - cS.y;                        \
                        const float num1 = 0.5f * dAB + SSIM_C1;              \
                        const float num2 = 0.5f * (dPQ - dAB) + SSIM_C2;      \
                        const float den1 = 0.5f * sAB + SSIM_C1;              \
                        const float den2 = 0.5f * (sPQ - sAB) + SSIM_C2;      \
                        lsum += (num1 * num2) *                               \
                                __builtin_amdgcn_rcpf(den1 * den2);           \
                    }                                                         \
                }                                                             \
            }                                                                 \
            __syncthreads();                                                  \
        }                                                                     \
    }

    for (int t2 = 0; t2 < 2; ++t2) {
        PAIR(0)  PAIR(1)  PAIR(2)  PAIR(3)  PAIR(4)  PAIR(5)  PAIR(6)
        PAIR(7)  PAIR(8)  PAIR(9)  PAIR(10) PAIR(11) PAIR(12) PAIR(13)
    }
#undef PAIR

    // deterministic block reduction
    red[tid] = lsum;
    __syncthreads();
    for (int off = 128; off > 0; off >>= 1) {
        if (tid < off) red[tid] += red[tid + off];
        __syncthreads();
    }
    if (tid == 0)
        partials[(blockIdx.z * gridDim.y + blockIdx.y) * gridDim.x + blockIdx.x] = red[0];
}

__global__ __launch_bounds__(256) void k_final(
    const float* __restrict__ partials, int n, float scale, float* __restrict__ out)
{
    __shared__ float red[256];
    float s = 0.f;
    for (int i = threadIdx.x; i < n; i += 256) s += partials[i];
    red[threadIdx.x] = s;
    __syncthreads();
    for (int off = 128; off > 0; off >>= 1) {
        if (threadIdx.x < off) red[threadIdx.x] += red[threadIdx.x + off];
        __syncthreads();
    }
    if (threadIdx.x == 0) out[0] = red[0] * scale;
}

extern "C" void kernel_launch(void* const* d_in, const int* in_sizes, int n_in,
                              void* d_out, int out_size, void* d_ws, size_t ws_size,
                              hipStream_t stream)
{
    const float* img1 = (const float*)d_in[0];
    const float* img2 = (const float*)d_in[1];
    float* out = (float*)d_out;
    float* partials = (float*)d_ws;

    Gw gw;
    {
        double gs[7], sum = 0.0;
        for (int i = 0; i < 7; ++i) { double x = i - 3; gs[i] = exp(-x * x / 4.5); sum += gs[i]; }
        for (int i = 0; i < 7; ++i) gw.g[i] = (float)(gs[i] / sum);
    }

    dim3 grid(256 / TW, 256 / TH, NB * NCH);   // 8 x 32 x 8 = 2048 blocks
    k_fused<<<grid, dim3(256), 0, stream>>>(img1, img2, gw, partials);
    k_final<<<dim3(1), dim3(256), 0, stream>>>(
        partials, (256 / TW) * (256 / TH) * NB * NCH, (float)(1.0 / 20971520.0), out);
}